// Round 1
// baseline (768.000 us; speedup 1.0000x reference)
//
#include <hip/hip_runtime.h>

#define NQ    15
#define DIM   32768
#define NTOK  32
#define NPQC  60
#define TPB   512
#define KREG  64      // DIM / TPB amplitudes per thread
#define CHUNK 16      // registers exchanged per LDS round (4 rounds)

// ---------- small template utilities (avoid <utility> in device code) ----------
template<int... Is> struct iseq {};
template<int N, int... Is> struct mkseq : mkseq<N-1, N-1, Is...> {};
template<int... Is> struct mkseq<0, Is...> { using type = iseq<Is...>; };

__device__ __forceinline__ float wsum(float v){
  #pragma unroll
  for (int m = 1; m < 64; m <<= 1) v += __shfl_xor(v, m, 64);
  return v;
}

// qubit w lives at flat bit fb = 14 - w  (axis 0 of the (2,)^15 tensor = MSB).
// amplitude index a = tid*KREG + r : bits 0..5 = r, bits 6..11 = lane, 12..14 = wave.
// CRX pass 1: seq j=0..14 -> i=14-j, ctrl=i, tgt=(i+1)%15
constexpr int crx1_fb(int j){ return j == 0 ? 14 : j - 1; }
constexpr int crx1_cb(int j){ return j; }
// CRX pass 2: seq k=0..14 -> i = (k==0)?14:(k-1), ctrl=i, tgt=(i-1)%15
constexpr int crx2_fb(int k){ return k == 0 ? 1 : (k == 1 ? 0 : 16 - k); }
constexpr int crx2_cb(int k){ return k == 0 ? 0 : (k == 1 ? 14 : 15 - k); }

// One gate. FB = flat bit of target, CB = flat bit of control (-1 = none).
// RY: n0 = c*a0 - s*a1 ; n1 = s*a0 + c*a1          (real coeffs)
// RX: n.re = c*m.re + s*p.im ; n.im = c*m.im - s*p.re   (symmetric both sides)
template<int FB, int CB, bool RX>
__device__ __forceinline__ void gate(float c, float s,
    float (&vr)[KREG], float (&vi)[KREG], const int tid,
    float* __restrict__ lr, float* __restrict__ li)
{
  if constexpr (FB < 6) {
    // register-local butterfly
    constexpr int m = 1 << FB;
    #pragma unroll
    for (int r0 = 0; r0 < KREG; ++r0) {
      if ((r0 & m) != 0) continue;
      const int r1 = r0 | m;
      bool a;
      if constexpr (CB < 0)      a = true;
      else if constexpr (CB < 6) a = ((r0 >> CB) & 1) != 0;
      else                       a = ((tid >> (CB - 6)) & 1) != 0;
      if (a) {
        if constexpr (RX) {
          float n0r = fmaf(c, vr[r0],  s * vi[r1]);
          float n0i = fmaf(c, vi[r0], -s * vr[r1]);
          float n1r = fmaf(c, vr[r1],  s * vi[r0]);
          float n1i = fmaf(c, vi[r1], -s * vr[r0]);
          vr[r0] = n0r; vi[r0] = n0i; vr[r1] = n1r; vi[r1] = n1i;
        } else {
          float n0r = fmaf(c, vr[r0], -s * vr[r1]);
          float n0i = fmaf(c, vi[r0], -s * vi[r1]);
          float n1r = fmaf(c, vr[r1],  s * vr[r0]);
          float n1i = fmaf(c, vi[r1],  s * vi[r0]);
          vr[r0] = n0r; vi[r0] = n0i; vr[r1] = n1r; vi[r1] = n1i;
        }
      }
    }
  } else if constexpr (FB < 12) {
    // lane-bit butterfly via shuffle
    constexpr int bm = 1 << (FB - 6);
    const int side = (tid >> (FB - 6)) & 1;
    const float sg = side ? s : -s;
    #pragma unroll
    for (int r = 0; r < KREG; ++r) {
      float pr = __shfl_xor(vr[r], bm, 64);
      float pi = __shfl_xor(vi[r], bm, 64);
      bool a;
      if constexpr (CB < 0)      a = true;
      else if constexpr (CB < 6) a = ((r >> CB) & 1) != 0;
      else                       a = ((tid >> (CB - 6)) & 1) != 0;
      float nr, ni;
      if constexpr (RX) { nr = fmaf(c, vr[r],  s * pi); ni = fmaf(c, vi[r], -s * pr); }
      else              { nr = fmaf(c, vr[r], sg * pr); ni = fmaf(c, vi[r], sg * pi); }
      if (a) { vr[r] = nr; vi[r] = ni; }
    }
  } else {
    // wave-bit butterfly via chunked LDS exchange (conflict-free layout)
    constexpr int bm = 1 << (FB - 6);     // tid-bit mask (64/128/256)
    const int side = (tid >> (FB - 6)) & 1;
    const float sg = side ? s : -s;
    const int ptid = tid ^ bm;
    #pragma unroll
    for (int ch = 0; ch < KREG / CHUNK; ++ch) {
      __syncthreads();
      #pragma unroll
      for (int j = 0; j < CHUNK; ++j) {
        lr[j * TPB + tid] = vr[ch * CHUNK + j];
        li[j * TPB + tid] = vi[ch * CHUNK + j];
      }
      __syncthreads();
      #pragma unroll
      for (int j = 0; j < CHUNK; ++j) {
        const int r = ch * CHUNK + j;
        float pr = lr[j * TPB + ptid];
        float pi = li[j * TPB + ptid];
        bool a;
        if constexpr (CB < 0)      a = true;
        else if constexpr (CB < 6) a = ((r >> CB) & 1) != 0;
        else                       a = ((tid >> (CB - 6)) & 1) != 0;
        float nr, ni;
        if constexpr (RX) { nr = fmaf(c, vr[r],  s * pi); ni = fmaf(c, vi[r], -s * pr); }
        else              { nr = fmaf(c, vr[r], sg * pr); ni = fmaf(c, vi[r], sg * pi); }
        if (a) { vr[r] = nr; vi[r] = ni; }
      }
    }
  }
}

template<int... Is>
__device__ __forceinline__ void evolve_seq(iseq<Is...>,
    float (&vr)[KREG], float (&vi)[KREG], int tid,
    float* __restrict__ lr, float* __restrict__ li,
    const float* __restrict__ csh, const float* __restrict__ snh)
{
  // pass 1: RY qubits 0..14                (params 0..14)
  (gate<14 - Is, -1, false>(csh[Is], snh[Is], vr, vi, tid, lr, li), ...);
  // pass 2: CRX i=14..0, ctrl=i tgt=(i+1)%15 (params 15..29)
  (gate<crx1_fb(Is), crx1_cb(Is), true>(csh[15 + Is], snh[15 + Is], vr, vi, tid, lr, li), ...);
  // pass 3: RY qubits 0..14                (params 30..44)
  (gate<14 - Is, -1, false>(csh[30 + Is], snh[30 + Is], vr, vi, tid, lr, li), ...);
  // pass 4: CRX i in [14,0..13], ctrl=i tgt=(i-1)%15 (params 45..59)
  (gate<crx2_fb(Is), crx2_cb(Is), true>(csh[45 + Is], snh[45 + Is], vr, vi, tid, lr, li), ...);
}

// mode: 0 = store evolved[bid*DIM + a]; 1 = plain store to out (final); 2 = atomicAdd lcu-weighted into out
__global__ __launch_bounds__(TPB, 2) void evolve_kernel(
    const float* __restrict__ angles, int astride,
    const float2* __restrict__ in_state,
    const float* __restrict__ norms, int slot, int mode,
    const float2* __restrict__ lcu,
    float2* __restrict__ out)
{
  __shared__ float lr[CHUNK * TPB];
  __shared__ float li[CHUNK * TPB];
  __shared__ float csh[NPQC], snh[NPQC];
  const int tid = threadIdx.x;

  {
    const float* ang = angles + (size_t)blockIdx.x * astride;
    if (tid < NPQC) {
      float a = ang[tid] * 0.5f;
      csh[tid] = cosf(a);
      snh[tid] = sinf(a);
    }
  }

  const float nv = norms[slot];
  bool small;
  if (mode == 1) {
    float qs = fmaxf(norms[4], 1e-8f);
    small = (nv / qs) < 1e-8f;     // snorm check on acc/qs ; non-small init = acc/||acc||
  } else {
    small = nv < 1e-8f;
  }
  const float inv = small ? 0.0f : 1.0f / nv;

  float vr[KREG], vi[KREG];
  const int base = tid * KREG;
  #pragma unroll
  for (int r = 0; r < KREG; ++r) {
    float2 v = in_state[base + r];
    vr[r] = small ? ((base + r) == 0 ? 1.0f : 0.0f) : v.x * inv;
    vi[r] = small ? 0.0f : v.y * inv;
  }
  __syncthreads();

  evolve_seq(typename mkseq<NQ>::type{}, vr, vi, tid, lr, li, csh, snh);

  if (mode == 0) {
    float2* o = out + (size_t)blockIdx.x * DIM;
    #pragma unroll
    for (int r = 0; r < KREG; ++r) o[base + r] = make_float2(vr[r], vi[r]);
  } else if (mode == 1) {
    #pragma unroll
    for (int r = 0; r < KREG; ++r) out[base + r] = make_float2(vr[r], vi[r]);
  } else {
    const float2 w = lcu[blockIdx.x];
    #pragma unroll
    for (int r = 0; r < KREG; ++r) {
      float xr = w.x * vr[r] - w.y * vi[r];
      float xi = w.x * vi[r] + w.y * vr[r];
      atomicAdd(&out[base + r].x, xr);
      atomicAdd(&out[base + r].y, xi);
    }
  }
}

__global__ void angles_kernel(const float* __restrict__ emb, const float* __restrict__ W,
                              const float* __restrict__ b, float* __restrict__ angles)
{
  const int p = blockIdx.x;      // 0..59
  const int t = blockIdx.y;      // 0..31
  const int lane = threadIdx.x;  // 64
  const float* er = emb + (size_t)t * 1024;
  const float* wr = W + (size_t)p * 1024;
  float s = 0.f;
  for (int i = lane; i < 1024; i += 64) s = fmaf(er[i], wr[i], s);
  s = wsum(s);
  if (lane == 0) angles[t * NPQC + p] = s + b[p];
}

__global__ void lcu_kernel(const float* __restrict__ ri, float2* __restrict__ lcu)
{
  const int t = threadIdx.x;   // 64 threads, one wave
  float re = 0.f, im = 0.f, mag = 0.f;
  if (t < NTOK) { re = ri[2 * t]; im = ri[2 * t + 1]; mag = sqrtf(re * re + im * im); }
  float ssum = wsum(mag);
  float denom = fmaxf(ssum, 1e-8f);
  if (t < NTOK) lcu[t] = make_float2(re / denom, im / denom);
}

__global__ void init_kernel(float2* __restrict__ monoA, float2* __restrict__ monoB,
                            float2* __restrict__ acc, const float* __restrict__ qsvt,
                            float* __restrict__ norms)
{
  const int d = blockIdx.x * blockDim.x + threadIdx.x;
  if (d < DIM) {
    monoA[d] = make_float2(d == 0 ? 1.f : 0.f, 0.f);
    monoB[d] = make_float2(0.f, 0.f);
    acc[d]   = make_float2(d == 0 ? qsvt[0] : 0.f, 0.f);
  }
  if (d == 0)
    norms[4] = fabsf(qsvt[0]) + fabsf(qsvt[1]) + fabsf(qsvt[2]) + fabsf(qsvt[3]);
}

__global__ void norm_kernel(const float2* __restrict__ v, float* __restrict__ norms, int slot)
{
  __shared__ float red[16];
  const int tid = threadIdx.x;           // 1024
  float s = 0.f;
  for (int d = tid; d < DIM; d += 1024) {
    float2 a = v[d];
    s = fmaf(a.x, a.x, fmaf(a.y, a.y, s));
  }
  s = wsum(s);
  const int lane = tid & 63, wv = tid >> 6;
  if (lane == 0) red[wv] = s;
  __syncthreads();
  if (tid == 0) {
    float t = 0.f;
    for (int i = 0; i < 16; ++i) t += red[i];
    norms[slot] = sqrtf(t);
  }
}

// path A: deterministic gather over evolved buffer
__global__ void combine_kernel(const float2* __restrict__ evolved,
                               const float2* __restrict__ lcu,
                               const float* __restrict__ norms, int slot,
                               const float* __restrict__ qsvt, int k,
                               float2* __restrict__ mono_out,
                               float2* __restrict__ acc)
{
  const int d = blockIdx.x * blockDim.x + threadIdx.x;
  const float nvv = norms[slot];
  const float scale = (nvv < 1e-8f) ? 1.0f : nvv;
  float sr = 0.f, si = 0.f;
  #pragma unroll
  for (int t = 0; t < NTOK; ++t) {
    float2 e = evolved[(size_t)t * DIM + d];
    float2 c = lcu[t];
    sr += e.x * c.x - e.y * c.y;
    si += e.x * c.y + e.y * c.x;
  }
  sr *= scale; si *= scale;
  mono_out[d] = make_float2(sr, si);
  const float q = qsvt[k];
  float2 a = acc[d];
  acc[d] = make_float2(fmaf(q, sr, a.x), fmaf(q, si, a.y));
}

// path B: finish after atomic accumulation (scale, acc update, zero next target)
__global__ void finish_kernel(float2* __restrict__ mono2, float2* __restrict__ acc,
                              float2* __restrict__ zero_buf,
                              const float* __restrict__ norms, int slot,
                              const float* __restrict__ qsvt, int k)
{
  const int d = blockIdx.x * blockDim.x + threadIdx.x;
  const float nvv = norms[slot];
  const float scale = (nvv < 1e-8f) ? 1.0f : nvv;
  float2 v = mono2[d];
  v.x *= scale; v.y *= scale;
  mono2[d] = v;
  const float q = qsvt[k];
  float2 a = acc[d];
  acc[d] = make_float2(fmaf(q, v.x, a.x), fmaf(q, v.y, a.y));
  zero_buf[d] = make_float2(0.f, 0.f);
}

__global__ void measure_kernel(const float2* __restrict__ st, float* __restrict__ out)
{
  __shared__ float rx[16], ryy[16], rz[16];
  const int tid = threadIdx.x;          // 1024
  const int lane = tid & 63, wv = tid >> 6;
  for (int w = 0; w < NQ; ++w) {
    const int fb = 14 - w;
    const int m = 1 << fb;
    float x = 0.f, y = 0.f, z = 0.f;
    for (int d = tid; d < DIM / 2; d += 1024) {
      int i0 = ((d >> fb) << (fb + 1)) | (d & (m - 1));
      float2 a0 = st[i0];
      float2 a1 = st[i0 | m];
      x += a0.x * a1.x + a0.y * a1.y;      // Re(conj(a0)*a1)
      y += a0.x * a1.y - a0.y * a1.x;      // Im(conj(a0)*a1)
      z += (a0.x * a0.x + a0.y * a0.y) - (a1.x * a1.x + a1.y * a1.y);
    }
    x = wsum(x); y = wsum(y); z = wsum(z);
    if (lane == 0) { rx[wv] = x; ryy[wv] = y; rz[wv] = z; }
    __syncthreads();
    if (tid == 0) {
      float sx = 0.f, sy = 0.f, sz = 0.f;
      for (int i = 0; i < 16; ++i) { sx += rx[i]; sy += ryy[i]; sz += rz[i]; }
      out[w] = 2.0f * sx; out[NQ + w] = 2.0f * sy; out[2 * NQ + w] = sz;
    }
    __syncthreads();
  }
}

extern "C" void kernel_launch(void* const* d_in, const int* in_sizes, int n_in,
                              void* d_out, int out_size, void* d_ws, size_t ws_size,
                              hipStream_t stream)
{
  const float* emb   = (const float*)d_in[0];   // [32][1024]
  const float* W     = (const float*)d_in[1];   // [60][1024]
  const float* b     = (const float*)d_in[2];   // [60]
  const float* qsvt  = (const float*)d_in[3];   // [4]
  const float* lcuri = (const float*)d_in[4];   // [32][2]
  const float* ffp   = (const float*)d_in[5];   // [60]
  float* out = (float*)d_out;                   // [45]

  char* ws = (char*)d_ws;
  size_t off = 0;
  auto nxt = [&](size_t bytes) { size_t o = off; off = (off + bytes + 255) & ~(size_t)255; return o; };
  const size_t o_ang = nxt(NTOK * NPQC * sizeof(float));
  const size_t o_lcu = nxt(NTOK * sizeof(float2));
  const size_t o_nrm = nxt(16 * sizeof(float));
  const size_t o_mA  = nxt((size_t)DIM * sizeof(float2));
  const size_t o_mB  = nxt((size_t)DIM * sizeof(float2));
  const size_t o_acc = nxt((size_t)DIM * sizeof(float2));
  const size_t o_fin = nxt((size_t)DIM * sizeof(float2));
  const size_t o_ev  = nxt((size_t)NTOK * DIM * sizeof(float2));
  const bool bigws = ws_size >= off;   // ~9.5 MB needed for path A

  float*  angles  = (float*)(ws + o_ang);
  float2* lcu     = (float2*)(ws + o_lcu);
  float*  norms   = (float*)(ws + o_nrm);
  float2* monoA   = (float2*)(ws + o_mA);
  float2* monoB   = (float2*)(ws + o_mB);
  float2* acc     = (float2*)(ws + o_acc);
  float2* fin     = (float2*)(ws + o_fin);
  float2* evolved = (float2*)(ws + o_ev);

  angles_kernel<<<dim3(NPQC, NTOK), 64, 0, stream>>>(emb, W, b, angles);
  lcu_kernel<<<1, 64, 0, stream>>>(lcuri, lcu);
  init_kernel<<<DIM / 256, 256, 0, stream>>>(monoA, monoB, acc, qsvt, norms);

  float2* mono = monoA;
  float2* mono2 = monoB;
  for (int k = 1; k <= 3; ++k) {
    norm_kernel<<<1, 1024, 0, stream>>>(mono, norms, k - 1);
    if (bigws) {
      evolve_kernel<<<NTOK, TPB, 0, stream>>>(angles, NPQC, mono, norms, k - 1, 0, lcu, evolved);
      combine_kernel<<<DIM / 256, 256, 0, stream>>>(evolved, lcu, norms, k - 1, qsvt, k, mono2, acc);
    } else {
      evolve_kernel<<<NTOK, TPB, 0, stream>>>(angles, NPQC, mono, norms, k - 1, 2, lcu, mono2);
      finish_kernel<<<DIM / 256, 256, 0, stream>>>(mono2, acc, mono, norms, k - 1, qsvt, k);
    }
    float2* tmp = mono; mono = mono2; mono2 = tmp;
  }

  norm_kernel<<<1, 1024, 0, stream>>>(acc, norms, 3);
  evolve_kernel<<<1, TPB, 0, stream>>>(ffp, 0, acc, norms, 3, 1, lcu, fin);
  measure_kernel<<<1, 1024, 0, stream>>>(fin, out);
}

// Round 2
// 333.996 us; speedup vs baseline: 2.2994x; 2.2994x over previous
//
#include <hip/hip_runtime.h>

#define NQ    15
#define DIM   32768
#define NTOK  32
#define NPQC  60
#define TPB   512
#define KREG  64      // old path: DIM / TPB amplitudes per thread
#define CHUNK 16      // old path: registers exchanged per LDS round

// ---------- small template utilities ----------
template<int... Is> struct iseq {};
template<int N, int... Is> struct mkseq : mkseq<N-1, N-1, Is...> {};
template<int... Is> struct mkseq<0, Is...> { using type = iseq<Is...>; };

__device__ __forceinline__ float wsum(float v){
  #pragma unroll
  for (int m = 1; m < 64; m <<= 1) v += __shfl_xor(v, m, 64);
  return v;
}

// ============================================================================
// NEW PATH: 8 blocks per state, 5 layout-permuted segments, all 256 CUs busy.
//
// Flat bit of qubit w is fb = 14 - w. Per segment s, a layout L_s assigns the
// 15 flat bits to {addr bits 0..11 (block-local), addr bits 12..14 (block id)}.
// Local position p -> storage kind:
//   p==0 -> reg bit0 ; p in 1..6 -> lane bit p-1 (shuffle) ;
//   p in 7..9 -> wave bit p-7 (tid bits 6..8, LDS exchange) ;
//   p==10 -> reg bit1 ; p==11 -> reg bit2.
// Thread tid, reg r (r = r0 + 2*r1 + 4*r2) holds local index
//   local = r0 + 2*tid + 1024*r1 + 2048*r2   (so float4 loads are coalesced).
// Layouts (flat_of_pos[0..11]; B = flats at addr bits 12,13,14):
//  L1: [3, 4,5,6,7,8,9, 10,11,12, 13,14]  B=[0,1,2]   ("storage layout")
//  L2: [14,4,5,6,7,0,1, 8,9,10,   2,3]    B=[11,12,13]
//  L3: [3, 4,5,6,14,13,12, 8,9,10, 7,11]  B=[0,1,2]
//  L4: [7, 6,14,13,12,0,1, 8,9,10, 2,11]  B=[3,4,5]
//  L5: [2, 0,1,4,5,6,7, 8,9,10,   3,11]   B=[12,13,14]
// Segment gate coverage (params): S1:0-11  S2:12-26  S3:27-41  S4:42-55  S5:56-59
// ============================================================================

template<int CPOS>
__device__ __forceinline__ bool cbit(int r, int tid, int blk){
  if constexpr (CPOS < 0)        return true;
  else if constexpr (CPOS == 0)  return (r & 1) != 0;
  else if constexpr (CPOS == 10) return (r & 2) != 0;
  else if constexpr (CPOS == 11) return (r & 4) != 0;
  else if constexpr (CPOS <= 9)  return ((tid >> (CPOS - 1)) & 1) != 0;
  else                           return ((blk >> (CPOS - 12)) & 1) != 0;
}

// reg-local butterfly (TPOS in {0,10,11})
template<int TPOS, int CPOS, bool RX>
__device__ __forceinline__ void gate_rl(float2 cs, float (&vr)[8], float (&vi)[8], int tid, int blk){
  constexpr int tm = (TPOS == 0) ? 1 : (TPOS == 10 ? 2 : 4);
  const float c = cs.x, s = cs.y;
  #pragma unroll
  for (int r0 = 0; r0 < 8; ++r0){
    if (r0 & tm) continue;
    const int r1 = r0 | tm;
    const bool act = cbit<CPOS>(r0, tid, blk);
    const float ar = vr[r0], ai = vi[r0], br = vr[r1], bi = vi[r1];
    if (act){
      if constexpr (RX){
        vr[r0] = fmaf(c, ar,  s * bi); vi[r0] = fmaf(c, ai, -s * br);
        vr[r1] = fmaf(c, br,  s * ai); vi[r1] = fmaf(c, bi, -s * ar);
      } else {
        vr[r0] = fmaf(c, ar, -s * br); vi[r0] = fmaf(c, ai, -s * bi);
        vr[r1] = fmaf(c, br,  s * ar); vi[r1] = fmaf(c, bi,  s * ai);
      }
    }
  }
}

// lane butterfly (TPOS in 1..6)
template<int TPOS, int CPOS, bool RX>
__device__ __forceinline__ void gate_ln(float2 cs, float (&vr)[8], float (&vi)[8], int tid, int blk){
  constexpr int bm = 1 << (TPOS - 1);
  const float c = cs.x, s = cs.y;
  const int side = (tid >> (TPOS - 1)) & 1;
  const float sg = side ? s : -s;
  #pragma unroll
  for (int r = 0; r < 8; ++r){
    const float pr = __shfl_xor(vr[r], bm, 64);
    const float pi = __shfl_xor(vi[r], bm, 64);
    const bool act = cbit<CPOS>(r, tid, blk);
    float nr, ni;
    if constexpr (RX){ nr = fmaf(c, vr[r],  s * pi); ni = fmaf(c, vi[r], -s * pr); }
    else             { nr = fmaf(c, vr[r], sg * pr); ni = fmaf(c, vi[r], sg * pi); }
    if (act){ vr[r] = nr; vi[r] = ni; }
  }
}

// wave butterfly via LDS (TPOS in 7..9 -> tid bits 6..8)
template<int TPOS, int CPOS, bool RX>
__device__ __forceinline__ void gate_wv(float2 cs, float (&vr)[8], float (&vi)[8], int tid, int blk, float2* ex){
  constexpr int tb = TPOS - 1;                // 6..8
  const int ptid = tid ^ (1 << tb);
  const float c = cs.x, s = cs.y;
  const int side = (tid >> tb) & 1;
  const float sg = side ? s : -s;
  __syncthreads();
  #pragma unroll
  for (int r = 0; r < 8; ++r) ex[(r << 9) | tid] = make_float2(vr[r], vi[r]);
  __syncthreads();
  #pragma unroll
  for (int r = 0; r < 8; ++r){
    const float2 p = ex[(r << 9) | ptid];
    const bool act = cbit<CPOS>(r, tid, blk);
    float nr, ni;
    if constexpr (RX){ nr = fmaf(c, vr[r],  s * p.y); ni = fmaf(c, vi[r], -s * p.x); }
    else             { nr = fmaf(c, vr[r], sg * p.x); ni = fmaf(c, vi[r], sg * p.y); }
    if (act){ vr[r] = nr; vi[r] = ni; }
  }
}

template<int TPOS, int CPOS, bool RX>
__device__ __forceinline__ void G(float2 cs, float (&vr)[8], float (&vi)[8], int tid, int blk, float2* ex){
  if constexpr (TPOS == 0 || TPOS == 10 || TPOS == 11) gate_rl<TPOS,CPOS,RX>(cs, vr, vi, tid, blk);
  else if constexpr (TPOS <= 6)                        gate_ln<TPOS,CPOS,RX>(cs, vr, vi, tid, blk);
  else                                                 gate_wv<TPOS,CPOS,RX>(cs, vr, vi, tid, blk, ex);
}

// common coalesced load of a block's 4096-amp slice (reader's own layout)
#define SEG_LOAD(SRC)                                                        \
  {                                                                          \
    const int t2 = tid << 1;                                                 \
    _Pragma("unroll")                                                        \
    for (int rh = 0; rh < 4; ++rh){                                          \
      const int r2 = rh >> 1, r1 = rh & 1, ra = (r1 << 1) | (r2 << 2);       \
      const float4 v = *reinterpret_cast<const float4*>(&(SRC)[(r2 << 11) + (r1 << 10) + t2]); \
      vr[ra] = v.x; vi[ra] = v.y; vr[ra + 1] = v.z; vi[ra + 1] = v.w;        \
    }                                                                        \
  }

// S1: reads mono/acc (L1), gates params 0..11, stores layout L2
__global__ __launch_bounds__(512) void seg1_k(const float2* __restrict__ in, float2* __restrict__ out,
    const float2* __restrict__ cs, int csStride, const float* __restrict__ parts, int np,
    int finalMode, const float* __restrict__ qsvt)
{
  __shared__ float2 ex[4096];
  __shared__ float2 gcs[12];
  const int tid = threadIdx.x, blk = blockIdx.x, tok = blockIdx.y;
  if (tid < 12) gcs[tid] = cs[tok * csStride + tid];
  bool small = false; float inv = 1.f;
  if (np > 0){
    const int lane = tid & 63;
    float p = lane < np ? parts[lane] : 0.f;
    const float nv = sqrtf(wsum(p));
    if (finalMode){
      const float qs = fmaxf(fabsf(qsvt[0]) + fabsf(qsvt[1]) + fabsf(qsvt[2]) + fabsf(qsvt[3]), 1e-8f);
      small = (nv / qs) < 1e-8f;
    } else small = nv < 1e-8f;
    inv = small ? 0.f : 1.f / nv;
  }
  float vr[8], vi[8];
  const float2* src = in + (blk << 12);
  {
    const int t2 = tid << 1;
    #pragma unroll
    for (int rh = 0; rh < 4; ++rh){
      const int r2 = rh >> 1, r1 = rh & 1, ra = (r1 << 1) | (r2 << 2);
      const float4 v = *reinterpret_cast<const float4*>(&src[(r2 << 11) + (r1 << 10) + t2]);
      vr[ra] = v.x * inv; vi[ra] = v.y * inv; vr[ra + 1] = v.z * inv; vi[ra + 1] = v.w * inv;
    }
  }
  if (small){
    #pragma unroll
    for (int r = 0; r < 8; ++r){ vr[r] = (blk == 0 && tid == 0 && r == 0) ? 1.f : 0.f; vi[r] = 0.f; }
  }
  __syncthreads();
  // RY t14..t3 (params 0..11): pos 11,10,9,8,7,6,5,4,3,2,1,0
  G<11,-1,false>(gcs[0], vr, vi, tid, blk, ex);
  G<10,-1,false>(gcs[1], vr, vi, tid, blk, ex);
  G< 9,-1,false>(gcs[2], vr, vi, tid, blk, ex);
  G< 8,-1,false>(gcs[3], vr, vi, tid, blk, ex);
  G< 7,-1,false>(gcs[4], vr, vi, tid, blk, ex);
  G< 6,-1,false>(gcs[5], vr, vi, tid, blk, ex);
  G< 5,-1,false>(gcs[6], vr, vi, tid, blk, ex);
  G< 4,-1,false>(gcs[7], vr, vi, tid, blk, ex);
  G< 3,-1,false>(gcs[8], vr, vi, tid, blk, ex);
  G< 2,-1,false>(gcs[9], vr, vi, tid, blk, ex);
  G< 1,-1,false>(gcs[10], vr, vi, tid, blk, ex);
  G< 0,-1,false>(gcs[11], vr, vi, tid, blk, ex);
  // store -> L2. W1: blk0->5 blk1->6 blk2->10 ; tid0..3->1..4, tid4..6->7..9, tid7->12, tid8->13 ; r0->11 r1->14 r2->0
  float2* dst = out + ((size_t)tok << 15);
  const int bb = ((blk & 1) << 5) | ((blk & 2) << 5) | ((blk & 4) << 8);
  const int tb = ((tid & 15) << 1) | ((tid & 112) << 3) | ((tid & 384) << 5);
  #pragma unroll
  for (int r1 = 0; r1 < 2; ++r1)
    #pragma unroll
    for (int r0 = 0; r0 < 2; ++r0){
      const int r = r0 | (r1 << 1);
      const int a = bb + tb + (r0 << 11) + (r1 << 14);
      *reinterpret_cast<float4*>(&dst[a]) = make_float4(vr[r], vi[r], vr[r + 4], vi[r + 4]);
    }
}

// S2: reads L2, gates params 12..26, stores L3
__global__ __launch_bounds__(512) void seg2_k(const float2* __restrict__ in, float2* __restrict__ out,
    const float2* __restrict__ cs, int csStride)
{
  __shared__ float2 ex[4096];
  __shared__ float2 gcs[15];
  const int tid = threadIdx.x, blk = blockIdx.x, tok = blockIdx.y;
  if (tid < 15) gcs[tid] = cs[tok * csStride + 12 + tid];
  float vr[8], vi[8];
  const float2* src = in + ((size_t)tok << 15) + (blk << 12);
  SEG_LOAD(src);
  __syncthreads();
  G<10,-1,false>(gcs[0], vr, vi, tid, blk, ex);   // RY t2
  G< 6,-1,false>(gcs[1], vr, vi, tid, blk, ex);   // RY t1
  G< 5,-1,false>(gcs[2], vr, vi, tid, blk, ex);   // RY t0
  G< 0, 5,true >(gcs[3], vr, vi, tid, blk, ex);   // CRX t14 c0
  G< 5, 6,true >(gcs[4], vr, vi, tid, blk, ex);   // CRX t0  c1
  G< 6,10,true >(gcs[5], vr, vi, tid, blk, ex);   // CRX t1  c2
  G<10,11,true >(gcs[6], vr, vi, tid, blk, ex);   // CRX t2  c3
  G<11, 1,true >(gcs[7], vr, vi, tid, blk, ex);   // CRX t3  c4
  G< 1, 2,true >(gcs[8], vr, vi, tid, blk, ex);   // CRX t4  c5
  G< 2, 3,true >(gcs[9], vr, vi, tid, blk, ex);   // CRX t5  c6
  G< 3, 4,true >(gcs[10], vr, vi, tid, blk, ex);  // CRX t6  c7
  G< 4, 7,true >(gcs[11], vr, vi, tid, blk, ex);  // CRX t7  c8
  G< 7, 8,true >(gcs[12], vr, vi, tid, blk, ex);  // CRX t8  c9  (LDS)
  G< 8, 9,true >(gcs[13], vr, vi, tid, blk, ex);  // CRX t9  c10 (LDS)
  G< 9,12,true >(gcs[14], vr, vi, tid, blk, ex);  // CRX t10 c11=blk0 (LDS)
  // store -> L3. W2: blk0->11 blk1->6 blk2->5 ; tid0..2->1..3, tid3->10, tid4->12, tid5->13, tid6..8->7..9 ; r0->4 r1->14 r2->0
  float2* dst = out + ((size_t)tok << 15);
  const int bb = ((blk & 1) << 11) | ((blk & 2) << 5) | ((blk & 4) << 3);
  const int tb = ((tid & 7) << 1) | ((tid & 8) << 7) | ((tid & 16) << 8) | ((tid & 32) << 8) | ((tid & 448) << 1);
  #pragma unroll
  for (int r1 = 0; r1 < 2; ++r1)
    #pragma unroll
    for (int r0 = 0; r0 < 2; ++r0){
      const int r = r0 | (r1 << 1);
      const int a = bb + tb + (r0 << 4) + (r1 << 14);
      *reinterpret_cast<float4*>(&dst[a]) = make_float4(vr[r], vi[r], vr[r + 4], vi[r + 4]);
    }
}

// S3: reads L3, gates params 27..41, stores L4
__global__ __launch_bounds__(512) void seg3_k(const float2* __restrict__ in, float2* __restrict__ out,
    const float2* __restrict__ cs, int csStride)
{
  __shared__ float2 ex[4096];
  __shared__ float2 gcs[15];
  const int tid = threadIdx.x, blk = blockIdx.x, tok = blockIdx.y;
  if (tid < 15) gcs[tid] = cs[tok * csStride + 27 + tid];
  float vr[8], vi[8];
  const float2* src = in + ((size_t)tok << 15) + (blk << 12);
  SEG_LOAD(src);
  __syncthreads();
  G<11, 6,true >(gcs[0], vr, vi, tid, blk, ex);   // CRX t11 c12
  G< 6, 5,true >(gcs[1], vr, vi, tid, blk, ex);   // CRX t12 c13
  G< 5, 4,true >(gcs[2], vr, vi, tid, blk, ex);   // CRX t13 c14
  G< 4,-1,false>(gcs[3], vr, vi, tid, blk, ex);   // RY t14
  G< 5,-1,false>(gcs[4], vr, vi, tid, blk, ex);   // RY t13
  G< 6,-1,false>(gcs[5], vr, vi, tid, blk, ex);   // RY t12
  G<11,-1,false>(gcs[6], vr, vi, tid, blk, ex);   // RY t11
  G< 9,-1,false>(gcs[7], vr, vi, tid, blk, ex);   // RY t10 (LDS)
  G< 8,-1,false>(gcs[8], vr, vi, tid, blk, ex);   // RY t9  (LDS)
  G< 7,-1,false>(gcs[9], vr, vi, tid, blk, ex);   // RY t8  (LDS)
  G<10,-1,false>(gcs[10], vr, vi, tid, blk, ex);  // RY t7
  G< 3,-1,false>(gcs[11], vr, vi, tid, blk, ex);  // RY t6
  G< 2,-1,false>(gcs[12], vr, vi, tid, blk, ex);  // RY t5
  G< 1,-1,false>(gcs[13], vr, vi, tid, blk, ex);  // RY t4
  G< 0,-1,false>(gcs[14], vr, vi, tid, blk, ex);  // RY t3
  // store -> L4. W3: blk0->5 blk1->6 blk2->10 ; tid0->13 tid1->14 tid2..5->1..4 tid6..8->7..9 ; r0->12 r1->0 r2->11
  float2* dst = out + ((size_t)tok << 15);
  const int bb = ((blk & 1) << 5) | ((blk & 2) << 5) | ((blk & 4) << 8);
  const int tb = ((tid & 1) << 13) | ((tid & 2) << 13) | ((tid & 60) >> 1) | ((tid & 448) << 1);
  #pragma unroll
  for (int r2 = 0; r2 < 2; ++r2)
    #pragma unroll
    for (int r0 = 0; r0 < 2; ++r0){
      const int r = r0 | (r2 << 2);
      const int a = bb + tb + (r0 << 12) + (r2 << 11);
      *reinterpret_cast<float4*>(&dst[a]) = make_float4(vr[r], vi[r], vr[r + 2], vi[r + 2]);
    }
}

// S4: reads L4, gates params 42..55, stores L5
__global__ __launch_bounds__(512) void seg4_k(const float2* __restrict__ in, float2* __restrict__ out,
    const float2* __restrict__ cs, int csStride)
{
  __shared__ float2 ex[4096];
  __shared__ float2 gcs[14];
  const int tid = threadIdx.x, blk = blockIdx.x, tok = blockIdx.y;
  if (tid < 14) gcs[tid] = cs[tok * csStride + 42 + tid];
  float vr[8], vi[8];
  const float2* src = in + ((size_t)tok << 15) + (blk << 12);
  SEG_LOAD(src);
  __syncthreads();
  G<10,-1,false>(gcs[0], vr, vi, tid, blk, ex);   // RY t2
  G< 6,-1,false>(gcs[1], vr, vi, tid, blk, ex);   // RY t1
  G< 5,-1,false>(gcs[2], vr, vi, tid, blk, ex);   // RY t0
  G< 6, 5,true >(gcs[3], vr, vi, tid, blk, ex);   // CRX t1  c0
  G< 5, 2,true >(gcs[4], vr, vi, tid, blk, ex);   // CRX t0  c14
  G< 2, 3,true >(gcs[5], vr, vi, tid, blk, ex);   // CRX t14 c13
  G< 3, 4,true >(gcs[6], vr, vi, tid, blk, ex);   // CRX t13 c12
  G< 4,11,true >(gcs[7], vr, vi, tid, blk, ex);   // CRX t12 c11
  G<11, 9,true >(gcs[8], vr, vi, tid, blk, ex);   // CRX t11 c10
  G< 9, 8,true >(gcs[9], vr, vi, tid, blk, ex);   // CRX t10 c9 (LDS)
  G< 8, 7,true >(gcs[10], vr, vi, tid, blk, ex);  // CRX t9  c8 (LDS)
  G< 7, 0,true >(gcs[11], vr, vi, tid, blk, ex);  // CRX t8  c7 (LDS)
  G< 0, 1,true >(gcs[12], vr, vi, tid, blk, ex);  // CRX t7  c6
  G< 1,14,true >(gcs[13], vr, vi, tid, blk, ex);  // CRX t6  c5=blk2
  // store -> L5. W4: blk0->10 blk1->3 blk2->4 ; tid0->5 tid1->14 tid2->13 tid3->12 tid4->1 tid5->2 tid6..8->7..9 ; r0->6 r1->0 r2->11
  float2* dst = out + ((size_t)tok << 15);
  const int bb = ((blk & 1) << 10) | ((blk & 2) << 2) | ((blk & 4) << 2);
  const int tb = ((tid & 1) << 5) | ((tid & 2) << 13) | ((tid & 4) << 11) | ((tid & 8) << 9)
               | ((tid & 48) >> 3) | ((tid & 448) << 1);
  #pragma unroll
  for (int r2 = 0; r2 < 2; ++r2)
    #pragma unroll
    for (int r0 = 0; r0 < 2; ++r0){
      const int r = r0 | (r2 << 2);
      const int a = bb + tb + (r0 << 6) + (r2 << 11);
      *reinterpret_cast<float4*>(&dst[a]) = make_float4(vr[r], vi[r], vr[r + 2], vi[r + 2]);
    }
}

// S5: reads L5, gates params 56..59, stores L1 (storage layout)
__global__ __launch_bounds__(512) void seg5_k(const float2* __restrict__ in, float2* __restrict__ out,
    const float2* __restrict__ cs, int csStride)
{
  __shared__ float2 ex[4096];
  __shared__ float2 gcs[4];
  const int tid = threadIdx.x, blk = blockIdx.x, tok = blockIdx.y;
  if (tid < 4) gcs[tid] = cs[tok * csStride + 56 + tid];
  float vr[8], vi[8];
  const float2* src = in + ((size_t)tok << 15) + (blk << 12);
  SEG_LOAD(src);
  __syncthreads();
  G< 4, 3,true >(gcs[0], vr, vi, tid, blk, ex);   // CRX t5 c4
  G< 3,10,true >(gcs[1], vr, vi, tid, blk, ex);   // CRX t4 c3
  G<10, 0,true >(gcs[2], vr, vi, tid, blk, ex);   // CRX t3 c2
  G< 0, 2,true >(gcs[3], vr, vi, tid, blk, ex);   // CRX t2 c1
  // store -> L1. W5: blk->9..11 ; tid0->12 tid1->13 tid2..8->1..7 ; r0->14 r1->0 r2->8
  float2* dst = out + ((size_t)tok << 15);
  const int bb = blk << 9;
  const int tb = ((tid & 1) << 12) | ((tid & 2) << 12) | ((tid & 508) >> 1);
  #pragma unroll
  for (int r2 = 0; r2 < 2; ++r2)
    #pragma unroll
    for (int r0 = 0; r0 < 2; ++r0){
      const int r = r0 | (r2 << 2);
      const int a = bb + tb + (r0 << 14) + (r2 << 8);
      *reinterpret_cast<float4*>(&dst[a]) = make_float4(vr[r], vi[r], vr[r + 2], vi[r + 2]);
    }
}

// angles -> cos/sin table  csarr[t*60+p] = {cos(v/2), sin(v/2)}
__global__ void angles2_kernel(const float* __restrict__ emb, const float* __restrict__ W,
                               const float* __restrict__ b, float2* __restrict__ csarr)
{
  const int p = blockIdx.x, t = blockIdx.y, lane = threadIdx.x;
  const float* er = emb + (size_t)t * 1024;
  const float* wr = W + (size_t)p * 1024;
  float s = 0.f;
  for (int i = lane; i < 1024; i += 64) s = fmaf(er[i], wr[i], s);
  s = wsum(s);
  if (lane == 0){
    const float a = (s + b[p]) * 0.5f;
    csarr[t * NPQC + p] = make_float2(cosf(a), sinf(a));
  }
}

// lcu normalization + ff cos/sin
__global__ void prep_kernel(const float* __restrict__ ri, float2* __restrict__ lcu,
                            const float* __restrict__ ffp, float2* __restrict__ csf)
{
  const int t = threadIdx.x;   // 64
  float re = 0.f, im = 0.f, mag = 0.f;
  if (t < NTOK){ re = ri[2 * t]; im = ri[2 * t + 1]; mag = sqrtf(re * re + im * im); }
  const float ssum = wsum(mag);
  const float denom = fmaxf(ssum, 1e-8f);
  if (t < NTOK) lcu[t] = make_float2(re / denom, im / denom);
  if (t < NPQC){ const float a = ffp[t] * 0.5f; csf[t] = make_float2(cosf(a), sinf(a)); }
}

__global__ void init2_kernel(float2* __restrict__ monoA, float2* __restrict__ acc,
                             const float* __restrict__ qsvt)
{
  const int d = (blockIdx.x << 9) | threadIdx.x;
  monoA[d] = make_float2(d == 0 ? 1.f : 0.f, 0.f);
  acc[d]   = make_float2(d == 0 ? qsvt[0] : 0.f, 0.f);
}

// LCU combine + acc update + deterministic per-block norm partials
__global__ __launch_bounds__(512) void combine2_k(const float2* __restrict__ ev, const float2* __restrict__ lcu,
    const float* __restrict__ partsPrev, int np, const float* __restrict__ qsvt, int k,
    float2* __restrict__ mono_out, float2* __restrict__ acc,
    float* __restrict__ pM, float* __restrict__ pA)
{
  __shared__ float red[16];
  const int tid = threadIdx.x;
  const int d = (blockIdx.x << 9) | tid;
  float scale = 1.f;
  if (np > 0){
    const int lane = tid & 63;
    float p = lane < np ? partsPrev[lane] : 0.f;
    const float nv = sqrtf(wsum(p));
    scale = (nv < 1e-8f) ? 1.f : nv;
  }
  float sr = 0.f, si = 0.f;
  #pragma unroll
  for (int t = 0; t < NTOK; ++t){
    const float2 e = ev[((size_t)t << 15) + d];
    const float2 c = lcu[t];
    sr += e.x * c.x - e.y * c.y;
    si += e.x * c.y + e.y * c.x;
  }
  sr *= scale; si *= scale;
  mono_out[d] = make_float2(sr, si);
  const float q = qsvt[k];
  float2 a = acc[d];
  a = make_float2(fmaf(q, sr, a.x), fmaf(q, si, a.y));
  acc[d] = a;
  float m2 = fmaf(sr, sr, si * si);
  float a2 = fmaf(a.x, a.x, a.y * a.y);
  m2 = wsum(m2); a2 = wsum(a2);
  const int lane = tid & 63, wv = tid >> 6;
  if (lane == 0){ red[wv] = m2; red[8 + wv] = a2; }
  __syncthreads();
  if (tid == 0){
    float t1 = 0.f, t2 = 0.f;
    for (int i = 0; i < 8; ++i){ t1 += red[i]; t2 += red[8 + i]; }
    pM[blockIdx.x] = t1; pA[blockIdx.x] = t2;
  }
}

// measurement on L1-layout state. addr bit of flat fb: fb>=3 -> fb-3, else fb+12.
__global__ void measure_l1(const float2* __restrict__ st, float* __restrict__ out)
{
  __shared__ float rx[16], ryy[16], rz[16];
  const int tid = threadIdx.x;          // 1024
  const int lane = tid & 63, wv = tid >> 6;
  const int abit[15] = {11,10,9,8,7,6,5,4,3,2,1,0,14,13,12};  // per qubit w
  for (int w = 0; w < NQ; ++w){
    const int ab = abit[w];
    const int m = 1 << ab;
    float x = 0.f, y = 0.f, z = 0.f;
    for (int d = tid; d < DIM / 2; d += 1024){
      const int i0 = ((d >> ab) << (ab + 1)) | (d & (m - 1));
      const float2 a0 = st[i0];
      const float2 a1 = st[i0 | m];
      x += a0.x * a1.x + a0.y * a1.y;
      y += a0.x * a1.y - a0.y * a1.x;
      z += (a0.x * a0.x + a0.y * a0.y) - (a1.x * a1.x + a1.y * a1.y);
    }
    x = wsum(x); y = wsum(y); z = wsum(z);
    if (lane == 0){ rx[wv] = x; ryy[wv] = y; rz[wv] = z; }
    __syncthreads();
    if (tid == 0){
      float sx = 0.f, sy = 0.f, sz = 0.f;
      for (int i = 0; i < 16; ++i){ sx += rx[i]; sy += ryy[i]; sz += rz[i]; }
      out[w] = 2.0f * sx; out[NQ + w] = 2.0f * sy; out[2 * NQ + w] = sz;
    }
    __syncthreads();
  }
}

// ============================================================================
// OLD PATH (fallback if workspace too small) — proven correct at 768 us.
// ============================================================================

constexpr int crx1_fb(int j){ return j == 0 ? 14 : j - 1; }
constexpr int crx1_cb(int j){ return j; }
constexpr int crx2_fb(int k){ return k == 0 ? 1 : (k == 1 ? 0 : 16 - k); }
constexpr int crx2_cb(int k){ return k == 0 ? 0 : (k == 1 ? 14 : 15 - k); }

template<int FB, int CB, bool RX>
__device__ __forceinline__ void gate(float c, float s,
    float (&vr)[KREG], float (&vi)[KREG], const int tid,
    float* __restrict__ lr, float* __restrict__ li)
{
  if constexpr (FB < 6) {
    constexpr int m = 1 << FB;
    #pragma unroll
    for (int r0 = 0; r0 < KREG; ++r0) {
      if ((r0 & m) != 0) continue;
      const int r1 = r0 | m;
      bool a;
      if constexpr (CB < 0)      a = true;
      else if constexpr (CB < 6) a = ((r0 >> CB) & 1) != 0;
      else                       a = ((tid >> (CB - 6)) & 1) != 0;
      if (a) {
        if constexpr (RX) {
          float n0r = fmaf(c, vr[r0],  s * vi[r1]);
          float n0i = fmaf(c, vi[r0], -s * vr[r1]);
          float n1r = fmaf(c, vr[r1],  s * vi[r0]);
          float n1i = fmaf(c, vi[r1], -s * vr[r0]);
          vr[r0] = n0r; vi[r0] = n0i; vr[r1] = n1r; vi[r1] = n1i;
        } else {
          float n0r = fmaf(c, vr[r0], -s * vr[r1]);
          float n0i = fmaf(c, vi[r0], -s * vi[r1]);
          float n1r = fmaf(c, vr[r1],  s * vr[r0]);
          float n1i = fmaf(c, vi[r1],  s * vi[r0]);
          vr[r0] = n0r; vi[r0] = n0i; vr[r1] = n1r; vi[r1] = n1i;
        }
      }
    }
  } else if constexpr (FB < 12) {
    constexpr int bm = 1 << (FB - 6);
    const int side = (tid >> (FB - 6)) & 1;
    const float sg = side ? s : -s;
    #pragma unroll
    for (int r = 0; r < KREG; ++r) {
      float pr = __shfl_xor(vr[r], bm, 64);
      float pi = __shfl_xor(vi[r], bm, 64);
      bool a;
      if constexpr (CB < 0)      a = true;
      else if constexpr (CB < 6) a = ((r >> CB) & 1) != 0;
      else                       a = ((tid >> (CB - 6)) & 1) != 0;
      float nr, ni;
      if constexpr (RX) { nr = fmaf(c, vr[r],  s * pi); ni = fmaf(c, vi[r], -s * pr); }
      else              { nr = fmaf(c, vr[r], sg * pr); ni = fmaf(c, vi[r], sg * pi); }
      if (a) { vr[r] = nr; vi[r] = ni; }
    }
  } else {
    constexpr int bm = 1 << (FB - 6);
    const int side = (tid >> (FB - 6)) & 1;
    const float sg = side ? s : -s;
    const int ptid = tid ^ bm;
    #pragma unroll
    for (int ch = 0; ch < KREG / CHUNK; ++ch) {
      __syncthreads();
      #pragma unroll
      for (int j = 0; j < CHUNK; ++j) {
        lr[j * TPB + tid] = vr[ch * CHUNK + j];
        li[j * TPB + tid] = vi[ch * CHUNK + j];
      }
      __syncthreads();
      #pragma unroll
      for (int j = 0; j < CHUNK; ++j) {
        const int r = ch * CHUNK + j;
        float pr = lr[j * TPB + ptid];
        float pi = li[j * TPB + ptid];
        bool a;
        if constexpr (CB < 0)      a = true;
        else if constexpr (CB < 6) a = ((r >> CB) & 1) != 0;
        else                       a = ((tid >> (CB - 6)) & 1) != 0;
        float nr, ni;
        if constexpr (RX) { nr = fmaf(c, vr[r],  s * pi); ni = fmaf(c, vi[r], -s * pr); }
        else              { nr = fmaf(c, vr[r], sg * pr); ni = fmaf(c, vi[r], sg * pi); }
        if (a) { vr[r] = nr; vi[r] = ni; }
      }
    }
  }
}

template<int... Is>
__device__ __forceinline__ void evolve_seq(iseq<Is...>,
    float (&vr)[KREG], float (&vi)[KREG], int tid,
    float* __restrict__ lr, float* __restrict__ li,
    const float* __restrict__ csh, const float* __restrict__ snh)
{
  (gate<14 - Is, -1, false>(csh[Is], snh[Is], vr, vi, tid, lr, li), ...);
  (gate<crx1_fb(Is), crx1_cb(Is), true>(csh[15 + Is], snh[15 + Is], vr, vi, tid, lr, li), ...);
  (gate<14 - Is, -1, false>(csh[30 + Is], snh[30 + Is], vr, vi, tid, lr, li), ...);
  (gate<crx2_fb(Is), crx2_cb(Is), true>(csh[45 + Is], snh[45 + Is], vr, vi, tid, lr, li), ...);
}

__global__ __launch_bounds__(TPB, 2) void evolve_kernel(
    const float* __restrict__ angles, int astride,
    const float2* __restrict__ in_state,
    const float* __restrict__ norms, int slot, int mode,
    const float2* __restrict__ lcu,
    float2* __restrict__ out)
{
  __shared__ float lr[CHUNK * TPB];
  __shared__ float li[CHUNK * TPB];
  __shared__ float csh[NPQC], snh[NPQC];
  const int tid = threadIdx.x;
  {
    const float* ang = angles + (size_t)blockIdx.x * astride;
    if (tid < NPQC) {
      float a = ang[tid] * 0.5f;
      csh[tid] = cosf(a);
      snh[tid] = sinf(a);
    }
  }
  const float nv = norms[slot];
  bool small;
  if (mode == 1) {
    float qs = fmaxf(norms[4], 1e-8f);
    small = (nv / qs) < 1e-8f;
  } else {
    small = nv < 1e-8f;
  }
  const float inv = small ? 0.0f : 1.0f / nv;
  float vr[KREG], vi[KREG];
  const int base = tid * KREG;
  #pragma unroll
  for (int r = 0; r < KREG; ++r) {
    float2 v = in_state[base + r];
    vr[r] = small ? ((base + r) == 0 ? 1.0f : 0.0f) : v.x * inv;
    vi[r] = small ? 0.0f : v.y * inv;
  }
  __syncthreads();
  evolve_seq(typename mkseq<NQ>::type{}, vr, vi, tid, lr, li, csh, snh);
  if (mode == 0) {
    float2* o = out + (size_t)blockIdx.x * DIM;
    #pragma unroll
    for (int r = 0; r < KREG; ++r) o[base + r] = make_float2(vr[r], vi[r]);
  } else if (mode == 1) {
    #pragma unroll
    for (int r = 0; r < KREG; ++r) out[base + r] = make_float2(vr[r], vi[r]);
  } else {
    const float2 w = lcu[blockIdx.x];
    #pragma unroll
    for (int r = 0; r < KREG; ++r) {
      float xr = w.x * vr[r] - w.y * vi[r];
      float xi = w.x * vi[r] + w.y * vr[r];
      atomicAdd(&out[base + r].x, xr);
      atomicAdd(&out[base + r].y, xi);
    }
  }
}

__global__ void angles_kernel(const float* __restrict__ emb, const float* __restrict__ W,
                              const float* __restrict__ b, float* __restrict__ angles)
{
  const int p = blockIdx.x, t = blockIdx.y, lane = threadIdx.x;
  const float* er = emb + (size_t)t * 1024;
  const float* wr = W + (size_t)p * 1024;
  float s = 0.f;
  for (int i = lane; i < 1024; i += 64) s = fmaf(er[i], wr[i], s);
  s = wsum(s);
  if (lane == 0) angles[t * NPQC + p] = s + b[p];
}

__global__ void lcu_kernel(const float* __restrict__ ri, float2* __restrict__ lcu)
{
  const int t = threadIdx.x;
  float re = 0.f, im = 0.f, mag = 0.f;
  if (t < NTOK) { re = ri[2 * t]; im = ri[2 * t + 1]; mag = sqrtf(re * re + im * im); }
  float ssum = wsum(mag);
  float denom = fmaxf(ssum, 1e-8f);
  if (t < NTOK) lcu[t] = make_float2(re / denom, im / denom);
}

__global__ void init_kernel(float2* __restrict__ monoA, float2* __restrict__ monoB,
                            float2* __restrict__ acc, const float* __restrict__ qsvt,
                            float* __restrict__ norms)
{
  const int d = blockIdx.x * blockDim.x + threadIdx.x;
  if (d < DIM) {
    monoA[d] = make_float2(d == 0 ? 1.f : 0.f, 0.f);
    monoB[d] = make_float2(0.f, 0.f);
    acc[d]   = make_float2(d == 0 ? qsvt[0] : 0.f, 0.f);
  }
  if (d == 0)
    norms[4] = fabsf(qsvt[0]) + fabsf(qsvt[1]) + fabsf(qsvt[2]) + fabsf(qsvt[3]);
}

__global__ void norm_kernel(const float2* __restrict__ v, float* __restrict__ norms, int slot)
{
  __shared__ float red[16];
  const int tid = threadIdx.x;
  float s = 0.f;
  for (int d = tid; d < DIM; d += 1024) {
    float2 a = v[d];
    s = fmaf(a.x, a.x, fmaf(a.y, a.y, s));
  }
  s = wsum(s);
  const int lane = tid & 63, wv = tid >> 6;
  if (lane == 0) red[wv] = s;
  __syncthreads();
  if (tid == 0) {
    float t = 0.f;
    for (int i = 0; i < 16; ++i) t += red[i];
    norms[slot] = sqrtf(t);
  }
}

__global__ void combine_kernel(const float2* __restrict__ evolved,
                               const float2* __restrict__ lcu,
                               const float* __restrict__ norms, int slot,
                               const float* __restrict__ qsvt, int k,
                               float2* __restrict__ mono_out,
                               float2* __restrict__ acc)
{
  const int d = blockIdx.x * blockDim.x + threadIdx.x;
  const float nvv = norms[slot];
  const float scale = (nvv < 1e-8f) ? 1.0f : nvv;
  float sr = 0.f, si = 0.f;
  #pragma unroll
  for (int t = 0; t < NTOK; ++t) {
    float2 e = evolved[(size_t)t * DIM + d];
    float2 c = lcu[t];
    sr += e.x * c.x - e.y * c.y;
    si += e.x * c.y + e.y * c.x;
  }
  sr *= scale; si *= scale;
  mono_out[d] = make_float2(sr, si);
  const float q = qsvt[k];
  float2 a = acc[d];
  acc[d] = make_float2(fmaf(q, sr, a.x), fmaf(q, si, a.y));
}

__global__ void finish_kernel(float2* __restrict__ mono2, float2* __restrict__ acc,
                              float2* __restrict__ zero_buf,
                              const float* __restrict__ norms, int slot,
                              const float* __restrict__ qsvt, int k)
{
  const int d = blockIdx.x * blockDim.x + threadIdx.x;
  const float nvv = norms[slot];
  const float scale = (nvv < 1e-8f) ? 1.0f : nvv;
  float2 v = mono2[d];
  v.x *= scale; v.y *= scale;
  mono2[d] = v;
  const float q = qsvt[k];
  float2 a = acc[d];
  acc[d] = make_float2(fmaf(q, v.x, a.x), fmaf(q, v.y, a.y));
  zero_buf[d] = make_float2(0.f, 0.f);
}

__global__ void measure_kernel(const float2* __restrict__ st, float* __restrict__ out)
{
  __shared__ float rx[16], ryy[16], rz[16];
  const int tid = threadIdx.x;
  const int lane = tid & 63, wv = tid >> 6;
  for (int w = 0; w < NQ; ++w) {
    const int fb = 14 - w;
    const int m = 1 << fb;
    float x = 0.f, y = 0.f, z = 0.f;
    for (int d = tid; d < DIM / 2; d += 1024) {
      int i0 = ((d >> fb) << (fb + 1)) | (d & (m - 1));
      float2 a0 = st[i0];
      float2 a1 = st[i0 | m];
      x += a0.x * a1.x + a0.y * a1.y;
      y += a0.x * a1.y - a0.y * a1.x;
      z += (a0.x * a0.x + a0.y * a0.y) - (a1.x * a1.x + a1.y * a1.y);
    }
    x = wsum(x); y = wsum(y); z = wsum(z);
    if (lane == 0) { rx[wv] = x; ryy[wv] = y; rz[wv] = z; }
    __syncthreads();
    if (tid == 0) {
      float sx = 0.f, sy = 0.f, sz = 0.f;
      for (int i = 0; i < 16; ++i) { sx += rx[i]; sy += ryy[i]; sz += rz[i]; }
      out[w] = 2.0f * sx; out[NQ + w] = 2.0f * sy; out[2 * NQ + w] = sz;
    }
    __syncthreads();
  }
}

// ============================================================================

extern "C" void kernel_launch(void* const* d_in, const int* in_sizes, int n_in,
                              void* d_out, int out_size, void* d_ws, size_t ws_size,
                              hipStream_t stream)
{
  const float* emb   = (const float*)d_in[0];
  const float* W     = (const float*)d_in[1];
  const float* b     = (const float*)d_in[2];
  const float* qsvt  = (const float*)d_in[3];
  const float* lcuri = (const float*)d_in[4];
  const float* ffp   = (const float*)d_in[5];
  float* out = (float*)d_out;

  char* ws = (char*)d_ws;
  size_t off = 0;
  auto nxt = [&](size_t bytes) { size_t o = off; off = (off + bytes + 255) & ~(size_t)255; return o; };

  // ---- new-path workspace ----
  const size_t o_cs   = nxt((size_t)NTOK * NPQC * sizeof(float2));
  const size_t o_csf  = nxt(NPQC * sizeof(float2));
  const size_t o_lcu2 = nxt(NTOK * sizeof(float2));
  const size_t o_pm   = nxt(3 * 64 * sizeof(float));
  const size_t o_pa   = nxt(64 * sizeof(float));
  const size_t o_mA2  = nxt((size_t)DIM * sizeof(float2));
  const size_t o_mB2  = nxt((size_t)DIM * sizeof(float2));
  const size_t o_acc2 = nxt((size_t)DIM * sizeof(float2));
  const size_t o_fin2 = nxt((size_t)DIM * sizeof(float2));
  const size_t o_bufA = nxt((size_t)NTOK * DIM * sizeof(float2));
  const size_t o_bufB = nxt((size_t)NTOK * DIM * sizeof(float2));
  const size_t newNeed = off;

  if (ws_size >= newNeed) {
    float2* csarr = (float2*)(ws + o_cs);
    float2* csf   = (float2*)(ws + o_csf);
    float2* lcu   = (float2*)(ws + o_lcu2);
    float*  pMbuf = (float*)(ws + o_pm);
    float*  pA    = (float*)(ws + o_pa);
    float2* monoA = (float2*)(ws + o_mA2);
    float2* monoB = (float2*)(ws + o_mB2);
    float2* acc   = (float2*)(ws + o_acc2);
    float2* fin   = (float2*)(ws + o_fin2);
    float2* bufA  = (float2*)(ws + o_bufA);
    float2* bufB  = (float2*)(ws + o_bufB);

    angles2_kernel<<<dim3(NPQC, NTOK), 64, 0, stream>>>(emb, W, b, csarr);
    prep_kernel<<<1, 64, 0, stream>>>(lcuri, lcu, ffp, csf);
    init2_kernel<<<64, 512, 0, stream>>>(monoA, acc, qsvt);

    float2* mIn = monoA;
    float2* mOut = monoB;
    const float* prevPM = nullptr;
    for (int k = 1; k <= 3; ++k) {
      const int np = prevPM ? 64 : 0;
      seg1_k<<<dim3(8, NTOK), 512, 0, stream>>>(mIn, bufA, csarr, NPQC, prevPM, np, 0, qsvt);
      seg2_k<<<dim3(8, NTOK), 512, 0, stream>>>(bufA, bufB, csarr, NPQC);
      seg3_k<<<dim3(8, NTOK), 512, 0, stream>>>(bufB, bufA, csarr, NPQC);
      seg4_k<<<dim3(8, NTOK), 512, 0, stream>>>(bufA, bufB, csarr, NPQC);
      seg5_k<<<dim3(8, NTOK), 512, 0, stream>>>(bufB, bufA, csarr, NPQC);
      float* pMk = pMbuf + (size_t)(k - 1) * 64;
      combine2_k<<<64, 512, 0, stream>>>(bufA, lcu, prevPM, np, qsvt, k, mOut, acc, pMk, pA);
      prevPM = pMk;
      float2* tmp = mIn; mIn = mOut; mOut = tmp;
    }

    // final evolution of acc with ff params
    seg1_k<<<dim3(8, 1), 512, 0, stream>>>(acc, bufA, csf, 0, pA, 64, 1, qsvt);
    seg2_k<<<dim3(8, 1), 512, 0, stream>>>(bufA, bufB, csf, 0);
    seg3_k<<<dim3(8, 1), 512, 0, stream>>>(bufB, bufA, csf, 0);
    seg4_k<<<dim3(8, 1), 512, 0, stream>>>(bufA, bufB, csf, 0);
    seg5_k<<<dim3(8, 1), 512, 0, stream>>>(bufB, fin, csf, 0);
    measure_l1<<<1, 1024, 0, stream>>>(fin, out);
    return;
  }

  // ---- old path (fallback) ----
  off = 0;
  const size_t o_ang = nxt(NTOK * NPQC * sizeof(float));
  const size_t o_lcu = nxt(NTOK * sizeof(float2));
  const size_t o_nrm = nxt(16 * sizeof(float));
  const size_t o_mA  = nxt((size_t)DIM * sizeof(float2));
  const size_t o_mB  = nxt((size_t)DIM * sizeof(float2));
  const size_t o_acc = nxt((size_t)DIM * sizeof(float2));
  const size_t o_fin = nxt((size_t)DIM * sizeof(float2));
  const size_t o_ev  = nxt((size_t)NTOK * DIM * sizeof(float2));
  const bool bigws = ws_size >= off;

  float*  angles  = (float*)(ws + o_ang);
  float2* lcu     = (float2*)(ws + o_lcu);
  float*  norms   = (float*)(ws + o_nrm);
  float2* monoA   = (float2*)(ws + o_mA);
  float2* monoB   = (float2*)(ws + o_mB);
  float2* acc     = (float2*)(ws + o_acc);
  float2* fin     = (float2*)(ws + o_fin);
  float2* evolved = (float2*)(ws + o_ev);

  angles_kernel<<<dim3(NPQC, NTOK), 64, 0, stream>>>(emb, W, b, angles);
  lcu_kernel<<<1, 64, 0, stream>>>(lcuri, lcu);
  init_kernel<<<DIM / 256, 256, 0, stream>>>(monoA, monoB, acc, qsvt, norms);

  float2* mono = monoA;
  float2* mono2 = monoB;
  for (int k = 1; k <= 3; ++k) {
    norm_kernel<<<1, 1024, 0, stream>>>(mono, norms, k - 1);
    if (bigws) {
      evolve_kernel<<<NTOK, TPB, 0, stream>>>(angles, NPQC, mono, norms, k - 1, 0, lcu, evolved);
      combine_kernel<<<DIM / 256, 256, 0, stream>>>(evolved, lcu, norms, k - 1, qsvt, k, mono2, acc);
    } else {
      evolve_kernel<<<NTOK, TPB, 0, stream>>>(angles, NPQC, mono, norms, k - 1, 2, lcu, mono2);
      finish_kernel<<<DIM / 256, 256, 0, stream>>>(mono2, acc, mono, norms, k - 1, qsvt, k);
    }
    float2* tmp = mono; mono = mono2; mono2 = tmp;
  }

  norm_kernel<<<1, 1024, 0, stream>>>(acc, norms, 3);
  evolve_kernel<<<1, TPB, 0, stream>>>(ffp, 0, acc, norms, 3, 1, lcu, fin);
  measure_kernel<<<1, 1024, 0, stream>>>(fin, out);
}